// Round 1
// baseline (1107.590 us; speedup 1.0000x reference)
//
#include <hip/hip_runtime.h>
#include <math.h>

#define NN 20000        // nodes
#define NE 320000       // edges
#define HID 128
#define IN_DIM 192
#define NODE_IN 64

__device__ __forceinline__ float sigmoidf(float x) {
    return __builtin_amdgcn_rcpf(1.0f + __expf(-x));
}

// ---------------- generic fp32 GEMM: C[M,N] = act(A[M,K] @ B[K,N] (+bias)) ----------
// BM=BN=64, BK=16, 256 threads, 4x4 microtile per thread.
template<bool CONCAT_A, bool RELU, bool BIAS>
__launch_bounds__(256)
__global__ void gemm_f32(const float* __restrict__ A0, const float* __restrict__ A1,
                         const float* __restrict__ B, const float* __restrict__ bias,
                         float* __restrict__ C, int M, int N, int K)
{
    __shared__ float As[16][68];   // [k][m], padded: store bank-conflict-free, rows 16B-aligned
    __shared__ float Bs[16][68];   // [k][n]
    const int tid = threadIdx.x;
    const int tx = tid & 15;       // col group
    const int ty = tid >> 4;       // row group
    const int m0 = blockIdx.x * 64;
    const int n0 = blockIdx.y * 64;
    float acc[4][4] = {};

    for (int k0 = 0; k0 < K; k0 += 16) {
        // A tile 64x16 (1024 elems, 4 per thread), stored transposed As[k][m]
        #pragma unroll
        for (int i = 0; i < 4; ++i) {
            int g = tid + i * 256;
            int r = g >> 4;
            int c = g & 15;
            int mr = m0 + r;
            int k  = k0 + c;
            float v = 0.f;
            if (mr < M) {
                if (CONCAT_A) v = (k < 128) ? A0[mr * 128 + k] : A1[mr * 128 + (k - 128)];
                else          v = A0[mr * K + k];
            }
            As[c][r] = v;
        }
        // B tile 16x64
        #pragma unroll
        for (int i = 0; i < 4; ++i) {
            int g = tid + i * 256;
            int kr = g >> 6;
            int c  = g & 63;
            Bs[kr][c] = B[(k0 + kr) * N + (n0 + c)];
        }
        __syncthreads();
        #pragma unroll
        for (int kk = 0; kk < 16; ++kk) {
            float4 a = *(const float4*)&As[kk][ty * 4];
            float4 b = *(const float4*)&Bs[kk][tx * 4];
            float av[4] = {a.x, a.y, a.z, a.w};
            float bv[4] = {b.x, b.y, b.z, b.w};
            #pragma unroll
            for (int i = 0; i < 4; ++i)
                #pragma unroll
                for (int j = 0; j < 4; ++j)
                    acc[i][j] = fmaf(av[i], bv[j], acc[i][j]);
        }
        __syncthreads();
    }
    #pragma unroll
    for (int i = 0; i < 4; ++i) {
        int row = m0 + ty * 4 + i;
        if (row < M) {
            #pragma unroll
            for (int j = 0; j < 4; ++j) {
                int col = n0 + tx * 4 + j;
                float v = acc[i][j];
                if (BIAS) v += bias[col];
                if (RELU) v = fmaxf(v, 0.f);
                C[row * N + col] = v;
            }
        }
    }
}

// -------- node weight: nw[n] = sigmoid(dot(h[n,:128], W2) + b2), one wave per node -----
__global__ void nw_kernel(const float* __restrict__ h, const float* __restrict__ W2,
                          const float* __restrict__ b2, float* __restrict__ nw)
{
    int n = blockIdx.x * 4 + (threadIdx.x >> 6);
    int l = threadIdx.x & 63;
    if (n >= NN) return;
    float p = h[n * 128 + l] * W2[l] + h[n * 128 + 64 + l] * W2[64 + l];
    #pragma unroll
    for (int off = 32; off > 0; off >>= 1)
        p += __shfl_down(p, off, 64);
    if (l == 0) nw[n] = sigmoidf(p + b2[0]);
}

// -------- degree histogram + per-edge D accumulation over 2E incidence slots -----------
__global__ void degdacc_kernel(const int* __restrict__ inc_n, const int* __restrict__ inc_e,
                               const float* __restrict__ nw, int* __restrict__ deg,
                               float* __restrict__ Dacc, int S)
{
    int s = blockIdx.x * blockDim.x + threadIdx.x;
    if (s >= S) return;
    int n = inc_e[s];
    atomicAdd(&deg[n], 1);
    atomicAdd(&Dacc[inc_n[s]], nw[n]);
}

// -------- single-block exclusive scan of deg -> off; also Binv = 1/deg ------------------
__global__ void scan_kernel(const int* __restrict__ deg, int* __restrict__ off,
                            float* __restrict__ Binv)
{
    __shared__ int part[1024];
    int t = threadIdx.x;
    const int C = (NN + 1023) / 1024;   // 20
    int base = t * C;
    int s = 0;
    for (int i = 0; i < C; ++i) {
        int idx = base + i;
        if (idx < NN) s += deg[idx];
    }
    part[t] = s;
    __syncthreads();
    for (int o = 1; o < 1024; o <<= 1) {
        int v = (t >= o) ? part[t - o] : 0;
        __syncthreads();
        part[t] += v;
        __syncthreads();
    }
    int excl = (t == 0) ? 0 : part[t - 1];
    for (int i = 0; i < C; ++i) {
        int idx = base + i;
        if (idx < NN) {
            off[idx] = excl;
            int d = deg[idx];
            excl += d;
            Binv[idx] = (d > 0) ? 1.0f / (float)d : 0.0f;
        }
    }
    if (t == 0) off[NN] = part[1023];
}

// -------- CSR fill: per incidence slot, append edge id to its node's list ---------------
__global__ void fill_kernel(const int* __restrict__ inc_n, const int* __restrict__ inc_e,
                            const int* __restrict__ off, int* __restrict__ cur,
                            int* __restrict__ csr, int S)
{
    int s = blockIdx.x * blockDim.x + threadIdx.x;
    if (s >= S) return;
    int n = inc_e[s];
    int p = atomicAdd(&cur[n], 1);
    csr[off[n] + p] = inc_n[s];
}

// -------- Dinv in place -----------------------------------------------------------------
__global__ void dinv_kernel(float* __restrict__ D)
{
    int j = blockIdx.x * blockDim.x + threadIdx.x;
    if (j >= NE) return;
    float d = D[j];
    D[j] = (d > 0.f) ? __builtin_amdgcn_rcpf(d) : 0.f;
}

// -------- agg0[n,c] = Binv[n] * sum_{j in csr(n)} er0[j,c] ------------------------------
// er0[j] = [edge_rep[j] (192) | 0.5*(nf[u_j]+nf[v_j]) (64)]
__global__ void agg0_kernel(const int* __restrict__ csr, const int* __restrict__ off,
                            const float* __restrict__ Binv, const float* __restrict__ er,
                            const float* __restrict__ nf, const int* __restrict__ ei,
                            float* __restrict__ agg0)
{
    int n = blockIdx.x;
    int c = threadIdx.x;
    int s0 = off[n], s1 = off[n + 1];
    float acc = 0.f;
    if (c < 192) {
        for (int s = s0; s < s1; ++s) {
            int j = csr[s];
            acc += er[j * 192 + c];
        }
    } else {
        int cc = c - 192;
        for (int s = s0; s < s1; ++s) {
            int j = csr[s];
            int u = ei[j], v = ei[NE + j];
            acc += 0.5f * (nf[u * 64 + cc] + nf[v * 64 + cc]);
        }
    }
    agg0[n * 256 + c] = acc * Binv[n];
}

// -------- agg1[n,c] = Binv[n] * sum_{j in csr(n)} sigmoid(Dinv[j]*(e1[n,c]+e1[o,c])+b1[c])
__global__ void agg1_kernel(const int* __restrict__ csr, const int* __restrict__ off,
                            const float* __restrict__ Binv, const float* __restrict__ Dinv,
                            const float* __restrict__ e1, const int* __restrict__ ei,
                            const float* __restrict__ b1, float* __restrict__ agg1)
{
    int n = blockIdx.x;
    int c = threadIdx.x;
    int s0 = off[n], s1 = off[n + 1];
    float myv = e1[n * 256 + c];
    float bc = b1[c];
    float acc = 0.f;
    for (int s = s0; s < s1; ++s) {
        int j = csr[s];
        int u = ei[j], v = ei[NE + j];
        int o = (u == n) ? v : u;
        float x = Dinv[j] * (myv + e1[o * 256 + c]) + bc;
        acc += sigmoidf(x);
    }
    agg1[n * 256 + c] = acc * Binv[n];
}

// -------- final: out[j,c] = sigmoid(Dinv[j]*(e2[u,c]+e2[v,c]) + b2[c]) ------------------
__global__ void out_kernel(const float* __restrict__ e2, const float* __restrict__ Dinv,
                           const int* __restrict__ ei, const float* __restrict__ b2,
                           float* __restrict__ out)
{
    int j = blockIdx.x * 2 + (threadIdx.x >> 7);
    int c = threadIdx.x & 127;
    int u = ei[j], v = ei[NE + j];
    float x = Dinv[j] * (e2[u * 128 + c] + e2[v * 128 + c]) + b2[c];
    out[j * 128 + c] = sigmoidf(x);
}

extern "C" void kernel_launch(void* const* d_in, const int* in_sizes, int n_in,
                              void* d_out, int out_size, void* d_ws, size_t ws_size,
                              hipStream_t stream)
{
    const int*   ei       = (const int*)  d_in[0];   // edge_index [2,E]
    const float* edge_rep = (const float*)d_in[1];   // [E,192]
    const float* x        = (const float*)d_in[2];   // [N,128]
    const int*   hyper    = (const int*)  d_in[3];   // [2,2E]
    const float* proto    = (const float*)d_in[4];   // [N,128]
    const float* nf       = (const float*)d_in[5];   // [N,64]
    const float* lin1_W   = (const float*)d_in[6];
    const float* lin1_b   = (const float*)d_in[7];
    const float* lin2_W   = (const float*)d_in[8];
    const float* lin2_b   = (const float*)d_in[9];
    const float* hc1_W    = (const float*)d_in[10];
    const float* hc1_b    = (const float*)d_in[11];
    const float* hc2_W    = (const float*)d_in[12];
    const float* hc2_b    = (const float*)d_in[13];
    float* out = (float*)d_out;

    const int S = 2 * NE;
    const int* inc_n = hyper;         // graph-edge ids
    const int* inc_e = hyper + S;     // node ids

    // ---- small scratch in ws (~14.5 MB) ----
    char* ws = (char*)d_ws;
    float* nw   = (float*)(ws);                 // 20000 f32          (pad to 81920 B)
    float* Dacc = (float*)(ws + 81920);         // 320000 f32 -> Dinv (1282048 B pad)
    int*   deg  = (int*)  (ws + 1363968);       // 20000 i32
    int*   off  = (int*)  (ws + 1445888);       // 20001 i32
    int*   cur  = (int*)  (ws + 1527808);       // 20000 i32
    float* Binv = (float*)(ws + 1609728);       // 20000 f32
    int*   csr  = (int*)  (ws + 1691648);       // 640000 i32 (2560000 B)
    float* e2   = (float*)(ws + 4251648);       // 20000x128 f32 (10.24 MB) -> ends ~14.5 MB

    // ---- big scratch inside d_out (163.84 MB; fully overwritten by out_kernel last) ----
    char* ob = (char*)d_out;
    float* agg = (float*)(ob);                  // 20000x256 f32 (20.48 MB)  agg0 then agg1
    float* e1  = (float*)(ob + 20971520);       // 20000x256 f32 (20.48 MB)
    float* h   = (float*)(ob + 41943040);       // 20000x128 f32 (10.24 MB)

    hipMemsetAsync(deg,  0, NN * sizeof(int),   stream);
    hipMemsetAsync(Dacc, 0, NE * sizeof(float), stream);
    hipMemsetAsync(cur,  0, NN * sizeof(int),   stream);

    // 1) h = relu([x|proto] @ lin1_W + lin1_b)      [20000,256]@[256,128]
    gemm_f32<true, true, true><<<dim3(313, 2), 256, 0, stream>>>(
        x, proto, lin1_W, lin1_b, h, NN, 128, 256);

    // 2) nw = sigmoid(h @ lin2_W + lin2_b)
    nw_kernel<<<5000, 256, 0, stream>>>(h, lin2_W, lin2_b, nw);

    // 3) degree + D accumulation
    degdacc_kernel<<<(S + 255) / 256, 256, 0, stream>>>(inc_n, inc_e, nw, deg, Dacc, S);

    // 4) offsets + Binv
    scan_kernel<<<1, 1024, 0, stream>>>(deg, off, Binv);

    // 5) CSR fill
    fill_kernel<<<(S + 255) / 256, 256, 0, stream>>>(inc_n, inc_e, off, cur, csr, S);

    // 6) Dinv in place
    dinv_kernel<<<(NE + 255) / 256, 256, 0, stream>>>(Dacc);

    // 7) agg0 (gather er0 per node, scale by Binv)
    agg0_kernel<<<NN, 256, 0, stream>>>(csr, off, Binv, edge_rep, nf, ei, agg);

    // 8) e1 = agg0 @ hc1_W                          [20000,256]@[256,256]
    gemm_f32<false, false, false><<<dim3(313, 4), 256, 0, stream>>>(
        agg, nullptr, hc1_W, nullptr, e1, NN, 256, 256);

    // 9) agg1 (sigmoid per incidence, aggregate, scale by Binv)
    agg1_kernel<<<NN, 256, 0, stream>>>(csr, off, Binv, Dacc, e1, ei, hc1_b, agg);

    // 10) e2 = agg1 @ hc2_W                         [20000,256]@[256,128]
    gemm_f32<false, false, false><<<dim3(313, 2), 256, 0, stream>>>(
        agg, nullptr, hc2_W, nullptr, e2, NN, 128, 256);

    // 11) final per-edge output (fully overwrites d_out)
    out_kernel<<<NE / 2, 256, 0, stream>>>(e2, Dacc, ei, hc2_b, out);
}

// Round 2
// 990.905 us; speedup vs baseline: 1.1178x; 1.1178x over previous
//
#include <hip/hip_runtime.h>
#include <math.h>

#define NN 20000        // nodes
#define NE 320000       // edges
#define HID 128
#define IN_DIM 192
#define NODE_IN 64

__device__ __forceinline__ float sigmoidf(float x) {
    return __builtin_amdgcn_rcpf(1.0f + __expf(-x));
}

// ---------------- generic fp32 GEMM: C[M,N] = act(A[M,K] @ B[K,N] (+bias)) ----------
// BM=BN=64, BK=16, 256 threads, 4x4 microtile per thread.
template<bool CONCAT_A, bool RELU, bool BIAS>
__launch_bounds__(256)
__global__ void gemm_f32(const float* __restrict__ A0, const float* __restrict__ A1,
                         const float* __restrict__ B, const float* __restrict__ bias,
                         float* __restrict__ C, int M, int N, int K)
{
    __shared__ float As[16][68];
    __shared__ float Bs[16][68];
    const int tid = threadIdx.x;
    const int tx = tid & 15;
    const int ty = tid >> 4;
    const int m0 = blockIdx.x * 64;
    const int n0 = blockIdx.y * 64;
    float acc[4][4] = {};

    for (int k0 = 0; k0 < K; k0 += 16) {
        #pragma unroll
        for (int i = 0; i < 4; ++i) {
            int g = tid + i * 256;
            int r = g >> 4;
            int c = g & 15;
            int mr = m0 + r;
            int k  = k0 + c;
            float v = 0.f;
            if (mr < M) {
                if (CONCAT_A) v = (k < 128) ? A0[mr * 128 + k] : A1[mr * 128 + (k - 128)];
                else          v = A0[mr * K + k];
            }
            As[c][r] = v;
        }
        #pragma unroll
        for (int i = 0; i < 4; ++i) {
            int g = tid + i * 256;
            int kr = g >> 6;
            int c  = g & 63;
            Bs[kr][c] = B[(k0 + kr) * N + (n0 + c)];
        }
        __syncthreads();
        #pragma unroll
        for (int kk = 0; kk < 16; ++kk) {
            float4 a = *(const float4*)&As[kk][ty * 4];
            float4 b = *(const float4*)&Bs[kk][tx * 4];
            float av[4] = {a.x, a.y, a.z, a.w};
            float bv[4] = {b.x, b.y, b.z, b.w};
            #pragma unroll
            for (int i = 0; i < 4; ++i)
                #pragma unroll
                for (int j = 0; j < 4; ++j)
                    acc[i][j] = fmaf(av[i], bv[j], acc[i][j]);
        }
        __syncthreads();
    }
    #pragma unroll
    for (int i = 0; i < 4; ++i) {
        int row = m0 + ty * 4 + i;
        if (row < M) {
            #pragma unroll
            for (int j = 0; j < 4; ++j) {
                int col = n0 + tx * 4 + j;
                float v = acc[i][j];
                if (BIAS) v += bias[col];
                if (RELU) v = fmaxf(v, 0.f);
                C[row * N + col] = v;
            }
        }
    }
}

// -------- node weight: nw[n] = sigmoid(dot(h[n,:128], W2) + b2), one wave per node -----
__global__ void nw_kernel(const float* __restrict__ h, const float* __restrict__ W2,
                          const float* __restrict__ b2, float* __restrict__ nw)
{
    int n = blockIdx.x * 4 + (threadIdx.x >> 6);
    int l = threadIdx.x & 63;
    if (n >= NN) return;
    float p = h[n * 128 + l] * W2[l] + h[n * 128 + 64 + l] * W2[64 + l];
    #pragma unroll
    for (int off = 32; off > 0; off >>= 1)
        p += __shfl_down(p, off, 64);
    if (l == 0) nw[n] = sigmoidf(p + b2[0]);
}

// -------- degree histogram over 2E incidence slots (inc_e[s] == ei[s] flat) ------------
__global__ void deg_kernel(const int* __restrict__ ei, int* __restrict__ deg)
{
    int s = blockIdx.x * blockDim.x + threadIdx.x;
    if (s >= 2 * NE) return;
    atomicAdd(&deg[ei[s]], 1);
}

// -------- Dinv[j] = 1 / (nw[u_j] + nw[v_j])  (sigmoid > 0 so no zero guard needed) ------
__global__ void dinv_kernel(const int* __restrict__ ei, const float* __restrict__ nw,
                            float* __restrict__ Dinv)
{
    int j = blockIdx.x * blockDim.x + threadIdx.x;
    if (j >= NE) return;
    float d = nw[ei[j]] + nw[ei[NE + j]];
    Dinv[j] = __builtin_amdgcn_rcpf(d);
}

// -------- single-block exclusive scan of deg -> off; also Binv = 1/deg ------------------
__global__ void scan_kernel(const int* __restrict__ deg, int* __restrict__ off,
                            float* __restrict__ Binv)
{
    __shared__ int part[1024];
    int t = threadIdx.x;
    const int C = (NN + 1023) / 1024;   // 20
    int base = t * C;
    int s = 0;
    for (int i = 0; i < C; ++i) {
        int idx = base + i;
        if (idx < NN) s += deg[idx];
    }
    part[t] = s;
    __syncthreads();
    for (int o = 1; o < 1024; o <<= 1) {
        int v = (t >= o) ? part[t - o] : 0;
        __syncthreads();
        part[t] += v;
        __syncthreads();
    }
    int excl = (t == 0) ? 0 : part[t - 1];
    for (int i = 0; i < C; ++i) {
        int idx = base + i;
        if (idx < NN) {
            off[idx] = excl;
            int d = deg[idx];
            excl += d;
            Binv[idx] = (d > 0) ? 1.0f / (float)d : 0.0f;
        }
    }
    if (t == 0) off[NN] = part[1023];
}

// -------- CSR fill with precomputed other-endpoint --------------------------------------
// incidence s: node n = ei[s]; edge j = s % NE; other endpoint o = ei[(s+NE) % 2NE]
__global__ void fill_kernel(const int* __restrict__ ei, const int* __restrict__ off,
                            int* __restrict__ cur, int* __restrict__ csr_j,
                            int* __restrict__ csr_o)
{
    int s = blockIdx.x * blockDim.x + threadIdx.x;
    if (s >= 2 * NE) return;
    int n = ei[s];
    int j = (s < NE) ? s : s - NE;
    int o = ei[(s < NE) ? s + NE : s - NE];
    int p = atomicAdd(&cur[n], 1);
    int w = off[n] + p;
    csr_j[w] = j;
    csr_o[w] = o;
}

// -------- agg0[n,c] = Binv[n] * sum_{edges j at n} er0[j,c] -----------------------------
// er0[j] = [edge_rep[j] (192) | 0.5*(nf[n]+nf[o_j]) (64)]
// 1024 threads: ep = tid>>8 (4-way edge parallel), c = tid&255 (channel)
__launch_bounds__(1024)
__global__ void agg0_kernel(const int* __restrict__ csr_j, const int* __restrict__ csr_o,
                            const int* __restrict__ off, const float* __restrict__ Binv,
                            const float* __restrict__ er, const float* __restrict__ nf,
                            float* __restrict__ agg0)
{
    __shared__ int sh_j[256];
    __shared__ int sh_o[256];
    __shared__ float red[4][256];
    int n = blockIdx.x;
    int tid = threadIdx.x;
    int ep = tid >> 8, c = tid & 255;
    int s0 = off[n], s1 = off[n + 1];
    float acc = 0.f;
    for (int base = s0; base < s1; base += 256) {
        int cnt = min(256, s1 - base);
        if (tid < cnt) {
            sh_j[tid] = csr_j[base + tid];
            sh_o[tid] = csr_o[base + tid];
        }
        __syncthreads();
        if (c < 192) {
            #pragma unroll 2
            for (int t = ep; t < cnt; t += 4)
                acc += er[sh_j[t] * 192 + c];
        } else {
            int cc = c - 192;
            #pragma unroll 2
            for (int t = ep; t < cnt; t += 4)
                acc += nf[sh_o[t] * 64 + cc];
        }
        __syncthreads();
    }
    red[ep][c] = acc;
    __syncthreads();
    if (ep == 0) {
        float tot = red[0][c] + red[1][c] + red[2][c] + red[3][c];
        if (c >= 192) {
            float deg = (float)(s1 - s0);
            tot = 0.5f * (tot + deg * nf[n * 64 + (c - 192)]);
        }
        agg0[n * 256 + c] = tot * Binv[n];
    }
}

// -------- agg1[n,c] = Binv[n] * sum_j sigmoid(Dinv[j]*(e1[n,c]+e1[o_j,c]) + b1[c]) ------
__launch_bounds__(1024)
__global__ void agg1_kernel(const int* __restrict__ csr_j, const int* __restrict__ csr_o,
                            const int* __restrict__ off, const float* __restrict__ Binv,
                            const float* __restrict__ Dinv, const float* __restrict__ e1,
                            const float* __restrict__ b1, float* __restrict__ agg1)
{
    __shared__ int sh_o[256];
    __shared__ float sh_d[256];
    __shared__ float red[4][256];
    int n = blockIdx.x;
    int tid = threadIdx.x;
    int ep = tid >> 8, c = tid & 255;
    int s0 = off[n], s1 = off[n + 1];
    float myv = e1[n * 256 + c];
    float bc = b1[c];
    float acc = 0.f;
    for (int base = s0; base < s1; base += 256) {
        int cnt = min(256, s1 - base);
        if (tid < cnt) {
            int jj = csr_j[base + tid];
            sh_o[tid] = csr_o[base + tid];
            sh_d[tid] = Dinv[jj];
        }
        __syncthreads();
        #pragma unroll 2
        for (int t = ep; t < cnt; t += 4) {
            float x = sh_d[t] * (myv + e1[sh_o[t] * 256 + c]) + bc;
            acc += sigmoidf(x);
        }
        __syncthreads();
    }
    red[ep][c] = acc;
    __syncthreads();
    if (ep == 0)
        agg1[n * 256 + c] = (red[0][c] + red[1][c] + red[2][c] + red[3][c]) * Binv[n];
}

// -------- final: out[j,c] = sigmoid(Dinv[j]*(e2[u,c]+e2[v,c]) + b2[c]) ------------------
__global__ void out_kernel(const float* __restrict__ e2, const float* __restrict__ Dinv,
                           const int* __restrict__ ei, const float* __restrict__ b2,
                           float* __restrict__ out)
{
    int j = blockIdx.x * 2 + (threadIdx.x >> 7);
    int c = threadIdx.x & 127;
    int u = ei[j], v = ei[NE + j];
    float x = Dinv[j] * (e2[u * 128 + c] + e2[v * 128 + c]) + b2[c];
    out[j * 128 + c] = sigmoidf(x);
}

extern "C" void kernel_launch(void* const* d_in, const int* in_sizes, int n_in,
                              void* d_out, int out_size, void* d_ws, size_t ws_size,
                              hipStream_t stream)
{
    const int*   ei       = (const int*)  d_in[0];   // edge_index [2,E]
    const float* edge_rep = (const float*)d_in[1];   // [E,192]
    const float* x        = (const float*)d_in[2];   // [N,128]
    const float* proto    = (const float*)d_in[4];   // [N,128]
    const float* nf       = (const float*)d_in[5];   // [N,64]
    const float* lin1_W   = (const float*)d_in[6];
    const float* lin1_b   = (const float*)d_in[7];
    const float* lin2_W   = (const float*)d_in[8];
    const float* lin2_b   = (const float*)d_in[9];
    const float* hc1_W    = (const float*)d_in[10];
    const float* hc1_b    = (const float*)d_in[11];
    const float* hc2_W    = (const float*)d_in[12];
    const float* hc2_b    = (const float*)d_in[13];
    float* out = (float*)d_out;

    const int S = 2 * NE;

    // ---- small scratch in ws (~12 MB) ----
    char* ws = (char*)d_ws;
    float* nw   = (float*)(ws);                 // 20000 f32 (pad 81920 B)
    float* Dinv = (float*)(ws + 81920);         // 320000 f32 (1.28 MB)
    int*   deg  = (int*)  (ws + 1363968);       // 20000 i32
    int*   off  = (int*)  (ws + 1445888);       // 20001 i32
    int*   cur  = (int*)  (ws + 1527808);       // 20000 i32
    float* Binv = (float*)(ws + 1609728);       // 20000 f32
    float* e2   = (float*)(ws + 1691648);       // 20000x128 f32 (10.24 MB)

    // ---- big scratch inside d_out (163.84 MB; fully overwritten by out_kernel last) ----
    char* ob = (char*)d_out;
    float* agg   = (float*)(ob);                // 20000x256 f32 (20.48 MB)
    float* e1    = (float*)(ob + 20971520);     // 20000x256 f32 (20.48 MB)
    float* h     = (float*)(ob + 41943040);     // 20000x128 f32 (10.24 MB)
    int*   csr_j = (int*)  (ob + 52428800);     // 640000 i32 (2.56 MB)
    int*   csr_o = (int*)  (ob + 54988800);     // 640000 i32 (2.56 MB)

    hipMemsetAsync(deg, 0, NN * sizeof(int), stream);
    hipMemsetAsync(cur, 0, NN * sizeof(int), stream);

    // 1) h = relu([x|proto] @ lin1_W + lin1_b)      [20000,256]@[256,128]
    gemm_f32<true, true, true><<<dim3(313, 2), 256, 0, stream>>>(
        x, proto, lin1_W, lin1_b, h, NN, 128, 256);

    // 2) nw = sigmoid(h @ lin2_W + lin2_b)
    nw_kernel<<<5000, 256, 0, stream>>>(h, lin2_W, lin2_b, nw);

    // 3) degree histogram
    deg_kernel<<<(S + 255) / 256, 256, 0, stream>>>(ei, deg);

    // 4) Dinv per edge (no atomics)
    dinv_kernel<<<(NE + 255) / 256, 256, 0, stream>>>(ei, nw, Dinv);

    // 5) offsets + Binv
    scan_kernel<<<1, 1024, 0, stream>>>(deg, off, Binv);

    // 6) CSR fill (edge id + other endpoint)
    fill_kernel<<<(S + 255) / 256, 256, 0, stream>>>(ei, off, cur, csr_j, csr_o);

    // 7) agg0
    agg0_kernel<<<NN, 1024, 0, stream>>>(csr_j, csr_o, off, Binv, edge_rep, nf, agg);

    // 8) e1 = agg0 @ hc1_W                          [20000,256]@[256,256]
    gemm_f32<false, false, false><<<dim3(313, 4), 256, 0, stream>>>(
        agg, nullptr, hc1_W, nullptr, e1, NN, 256, 256);

    // 9) agg1
    agg1_kernel<<<NN, 1024, 0, stream>>>(csr_j, csr_o, off, Binv, Dinv, e1, hc1_b, agg);

    // 10) e2 = agg1 @ hc2_W                         [20000,256]@[256,128]
    gemm_f32<false, false, false><<<dim3(313, 2), 256, 0, stream>>>(
        agg, nullptr, hc2_W, nullptr, e2, NN, 128, 256);

    // 11) final per-edge output (fully overwrites d_out)
    out_kernel<<<NE / 2, 256, 0, stream>>>(e2, Dinv, ei, hc2_b, out);
}

// Round 3
// 879.412 us; speedup vs baseline: 1.2595x; 1.1268x over previous
//
#include <hip/hip_runtime.h>
#include <math.h>

#define NN 20000        // nodes
#define NE 320000       // edges
#define HID 128
#define IN_DIM 192
#define NODE_IN 64

__device__ __forceinline__ float sigmoidf(float x) {
    return __builtin_amdgcn_rcpf(1.0f + __expf(-x));
}

// ---------------- generic fp32 GEMM: C[M,N] = act(A[M,K] @ B[K,N] (+bias)) ----------
template<bool CONCAT_A, bool RELU, bool BIAS>
__launch_bounds__(256)
__global__ void gemm_f32(const float* __restrict__ A0, const float* __restrict__ A1,
                         const float* __restrict__ B, const float* __restrict__ bias,
                         float* __restrict__ C, int M, int N, int K)
{
    __shared__ float As[16][68];
    __shared__ float Bs[16][68];
    const int tid = threadIdx.x;
    const int tx = tid & 15;
    const int ty = tid >> 4;
    const int m0 = blockIdx.x * 64;
    const int n0 = blockIdx.y * 64;
    float acc[4][4] = {};

    for (int k0 = 0; k0 < K; k0 += 16) {
        #pragma unroll
        for (int i = 0; i < 4; ++i) {
            int g = tid + i * 256;
            int r = g >> 4;
            int c = g & 15;
            int mr = m0 + r;
            int k  = k0 + c;
            float v = 0.f;
            if (mr < M) {
                if (CONCAT_A) v = (k < 128) ? A0[mr * 128 + k] : A1[mr * 128 + (k - 128)];
                else          v = A0[mr * K + k];
            }
            As[c][r] = v;
        }
        #pragma unroll
        for (int i = 0; i < 4; ++i) {
            int g = tid + i * 256;
            int kr = g >> 6;
            int c  = g & 63;
            Bs[kr][c] = B[(k0 + kr) * N + (n0 + c)];
        }
        __syncthreads();
        #pragma unroll
        for (int kk = 0; kk < 16; ++kk) {
            float4 a = *(const float4*)&As[kk][ty * 4];
            float4 b = *(const float4*)&Bs[kk][tx * 4];
            float av[4] = {a.x, a.y, a.z, a.w};
            float bv[4] = {b.x, b.y, b.z, b.w};
            #pragma unroll
            for (int i = 0; i < 4; ++i)
                #pragma unroll
                for (int j = 0; j < 4; ++j)
                    acc[i][j] = fmaf(av[i], bv[j], acc[i][j]);
        }
        __syncthreads();
    }
    #pragma unroll
    for (int i = 0; i < 4; ++i) {
        int row = m0 + ty * 4 + i;
        if (row < M) {
            #pragma unroll
            for (int j = 0; j < 4; ++j) {
                int col = n0 + tx * 4 + j;
                float v = acc[i][j];
                if (BIAS) v += bias[col];
                if (RELU) v = fmaxf(v, 0.f);
                C[row * N + col] = v;
            }
        }
    }
}

// -------- node weight: nw[n] = sigmoid(dot(h[n,:128], W2) + b2), one wave per node -----
__global__ void nw_kernel(const float* __restrict__ h, const float* __restrict__ W2,
                          const float* __restrict__ b2, float* __restrict__ nw)
{
    int n = blockIdx.x * 4 + (threadIdx.x >> 6);
    int l = threadIdx.x & 63;
    if (n >= NN) return;
    float p = h[n * 128 + l] * W2[l] + h[n * 128 + 64 + l] * W2[64 + l];
    #pragma unroll
    for (int off = 32; off > 0; off >>= 1)
        p += __shfl_down(p, off, 64);
    if (l == 0) nw[n] = sigmoidf(p + b2[0]);
}

// -------- degree histogram over 2E incidence slots --------------------------------------
__global__ void deg_kernel(const int* __restrict__ ei, int* __restrict__ deg)
{
    int s = blockIdx.x * blockDim.x + threadIdx.x;
    if (s >= 2 * NE) return;
    atomicAdd(&deg[ei[s]], 1);
}

// -------- Dinv[j] = 1 / (nw[u_j] + nw[v_j]) ---------------------------------------------
__global__ void dinv_kernel(const int* __restrict__ ei, const float* __restrict__ nw,
                            float* __restrict__ Dinv)
{
    int j = blockIdx.x * blockDim.x + threadIdx.x;
    if (j >= NE) return;
    float d = nw[ei[j]] + nw[ei[NE + j]];
    Dinv[j] = __builtin_amdgcn_rcpf(d);
}

// -------- single-block exclusive scan of deg -> off; also Binv = 1/deg ------------------
__global__ void scan_kernel(const int* __restrict__ deg, int* __restrict__ off,
                            float* __restrict__ Binv)
{
    __shared__ int part[1024];
    int t = threadIdx.x;
    const int C = (NN + 1023) / 1024;   // 20
    int base = t * C;
    int s = 0;
    for (int i = 0; i < C; ++i) {
        int idx = base + i;
        if (idx < NN) s += deg[idx];
    }
    part[t] = s;
    __syncthreads();
    for (int o = 1; o < 1024; o <<= 1) {
        int v = (t >= o) ? part[t - o] : 0;
        __syncthreads();
        part[t] += v;
        __syncthreads();
    }
    int excl = (t == 0) ? 0 : part[t - 1];
    for (int i = 0; i < C; ++i) {
        int idx = base + i;
        if (idx < NN) {
            off[idx] = excl;
            int d = deg[idx];
            excl += d;
            Binv[idx] = (d > 0) ? 1.0f / (float)d : 0.0f;
        }
    }
    if (t == 0) off[NN] = part[1023];
}

// -------- CSR fill with precomputed other-endpoint --------------------------------------
__global__ void fill_kernel(const int* __restrict__ ei, const int* __restrict__ off,
                            int* __restrict__ cur, int* __restrict__ csr_j,
                            int* __restrict__ csr_o)
{
    int s = blockIdx.x * blockDim.x + threadIdx.x;
    if (s >= 2 * NE) return;
    int n = ei[s];
    int j = (s < NE) ? s : s - NE;
    int o = ei[(s < NE) ? s + NE : s - NE];
    int p = atomicAdd(&cur[n], 1);
    int w = off[n] + p;
    csr_j[w] = j;
    csr_o[w] = o;
}

// -------- agg0[n,c] = Binv[n] * sum_{edges j at n} er0[j,c] -----------------------------
// er0[j] = [edge_rep[j] (192) | 0.5*(nf[n]+nf[o_j]) (64)]
// 256 threads: c = tid; per-thread loop over all edges, 8-deep unroll for MLP.
__launch_bounds__(256)
__global__ void agg0_kernel(const int* __restrict__ csr_j, const int* __restrict__ csr_o,
                            const int* __restrict__ off, const float* __restrict__ Binv,
                            const float* __restrict__ er, const float* __restrict__ nf,
                            float* __restrict__ agg0)
{
    __shared__ int sh_j[256];
    __shared__ int sh_o[256];
    int n = blockIdx.x;
    int c = threadIdx.x;
    int s0 = off[n], s1 = off[n + 1];
    float a0 = 0.f, a1 = 0.f, a2 = 0.f, a3 = 0.f;
    for (int base = s0; base < s1; base += 256) {
        int cnt = min(256, s1 - base);
        if (c < cnt) {
            sh_j[c] = csr_j[base + c];
            sh_o[c] = csr_o[base + c];
        }
        __syncthreads();
        int t = 0;
        if (c < 192) {
            for (; t + 8 <= cnt; t += 8) {
                float v0 = er[sh_j[t + 0] * 192 + c];
                float v1 = er[sh_j[t + 1] * 192 + c];
                float v2 = er[sh_j[t + 2] * 192 + c];
                float v3 = er[sh_j[t + 3] * 192 + c];
                float v4 = er[sh_j[t + 4] * 192 + c];
                float v5 = er[sh_j[t + 5] * 192 + c];
                float v6 = er[sh_j[t + 6] * 192 + c];
                float v7 = er[sh_j[t + 7] * 192 + c];
                a0 += v0 + v4; a1 += v1 + v5; a2 += v2 + v6; a3 += v3 + v7;
            }
            for (; t < cnt; ++t) a0 += er[sh_j[t] * 192 + c];
        } else {
            int cc = c - 192;
            for (; t + 8 <= cnt; t += 8) {
                float v0 = nf[sh_o[t + 0] * 64 + cc];
                float v1 = nf[sh_o[t + 1] * 64 + cc];
                float v2 = nf[sh_o[t + 2] * 64 + cc];
                float v3 = nf[sh_o[t + 3] * 64 + cc];
                float v4 = nf[sh_o[t + 4] * 64 + cc];
                float v5 = nf[sh_o[t + 5] * 64 + cc];
                float v6 = nf[sh_o[t + 6] * 64 + cc];
                float v7 = nf[sh_o[t + 7] * 64 + cc];
                a0 += v0 + v4; a1 += v1 + v5; a2 += v2 + v6; a3 += v3 + v7;
            }
            for (; t < cnt; ++t) a0 += nf[sh_o[t] * 64 + cc];
        }
        __syncthreads();
    }
    float tot = (a0 + a1) + (a2 + a3);
    if (c >= 192) {
        float deg = (float)(s1 - s0);
        tot = 0.5f * (tot + deg * nf[n * 64 + (c - 192)]);
    }
    agg0[n * 256 + c] = tot * Binv[n];
}

// -------- agg1[n,c] = Binv[n] * sum_j sigmoid(Dinv[j]*(e1[n,c]+e1[o_j,c]) + b1[c]) ------
__launch_bounds__(256)
__global__ void agg1_kernel(const int* __restrict__ csr_j, const int* __restrict__ csr_o,
                            const int* __restrict__ off, const float* __restrict__ Binv,
                            const float* __restrict__ Dinv, const float* __restrict__ e1,
                            const float* __restrict__ b1, float* __restrict__ agg1)
{
    __shared__ int sh_o[256];
    __shared__ float sh_d[256];
    int n = blockIdx.x;
    int c = threadIdx.x;
    int s0 = off[n], s1 = off[n + 1];
    float myv = e1[n * 256 + c];
    float bc = b1[c];
    float a0 = 0.f, a1 = 0.f, a2 = 0.f, a3 = 0.f;
    for (int base = s0; base < s1; base += 256) {
        int cnt = min(256, s1 - base);
        if (c < cnt) {
            int jj = csr_j[base + c];
            sh_o[c] = csr_o[base + c];
            sh_d[c] = Dinv[jj];
        }
        __syncthreads();
        int t = 0;
        for (; t + 8 <= cnt; t += 8) {
            float v0 = e1[sh_o[t + 0] * 256 + c];
            float v1 = e1[sh_o[t + 1] * 256 + c];
            float v2 = e1[sh_o[t + 2] * 256 + c];
            float v3 = e1[sh_o[t + 3] * 256 + c];
            float v4 = e1[sh_o[t + 4] * 256 + c];
            float v5 = e1[sh_o[t + 5] * 256 + c];
            float v6 = e1[sh_o[t + 6] * 256 + c];
            float v7 = e1[sh_o[t + 7] * 256 + c];
            a0 += sigmoidf(fmaf(sh_d[t + 0], myv + v0, bc));
            a1 += sigmoidf(fmaf(sh_d[t + 1], myv + v1, bc));
            a2 += sigmoidf(fmaf(sh_d[t + 2], myv + v2, bc));
            a3 += sigmoidf(fmaf(sh_d[t + 3], myv + v3, bc));
            a0 += sigmoidf(fmaf(sh_d[t + 4], myv + v4, bc));
            a1 += sigmoidf(fmaf(sh_d[t + 5], myv + v5, bc));
            a2 += sigmoidf(fmaf(sh_d[t + 6], myv + v6, bc));
            a3 += sigmoidf(fmaf(sh_d[t + 7], myv + v7, bc));
        }
        for (; t < cnt; ++t) {
            float v = e1[sh_o[t] * 256 + c];
            a0 += sigmoidf(fmaf(sh_d[t], myv + v, bc));
        }
        __syncthreads();
    }
    agg1[n * 256 + c] = ((a0 + a1) + (a2 + a3)) * Binv[n];
}

// -------- final: out[j,c] = sigmoid(Dinv[j]*(e2[u,c]+e2[v,c]) + b2[c]) ------------------
__global__ void out_kernel(const float* __restrict__ e2, const float* __restrict__ Dinv,
                           const int* __restrict__ ei, const float* __restrict__ b2,
                           float* __restrict__ out)
{
    int j = blockIdx.x * 2 + (threadIdx.x >> 7);
    int c = threadIdx.x & 127;
    int u = ei[j], v = ei[NE + j];
    float x = Dinv[j] * (e2[u * 128 + c] + e2[v * 128 + c]) + b2[c];
    out[j * 128 + c] = sigmoidf(x);
}

extern "C" void kernel_launch(void* const* d_in, const int* in_sizes, int n_in,
                              void* d_out, int out_size, void* d_ws, size_t ws_size,
                              hipStream_t stream)
{
    const int*   ei       = (const int*)  d_in[0];   // edge_index [2,E]
    const float* edge_rep = (const float*)d_in[1];   // [E,192]
    const float* x        = (const float*)d_in[2];   // [N,128]
    const float* proto    = (const float*)d_in[4];   // [N,128]
    const float* nf       = (const float*)d_in[5];   // [N,64]
    const float* lin1_W   = (const float*)d_in[6];
    const float* lin1_b   = (const float*)d_in[7];
    const float* lin2_W   = (const float*)d_in[8];
    const float* lin2_b   = (const float*)d_in[9];
    const float* hc1_W    = (const float*)d_in[10];
    const float* hc1_b    = (const float*)d_in[11];
    const float* hc2_W    = (const float*)d_in[12];
    const float* hc2_b    = (const float*)d_in[13];
    float* out = (float*)d_out;

    const int S = 2 * NE;

    // ---- small scratch in ws ----
    char* ws = (char*)d_ws;
    float* nw   = (float*)(ws);                 // 20000 f32 (pad 81920 B)
    float* Dinv = (float*)(ws + 81920);         // 320000 f32 (1.28 MB)
    int*   deg  = (int*)  (ws + 1363968);       // 20000 i32
    int*   off  = (int*)  (ws + 1445888);       // 20001 i32
    int*   cur  = (int*)  (ws + 1527808);       // 20000 i32
    float* Binv = (float*)(ws + 1609728);       // 20000 f32
    float* e2   = (float*)(ws + 1691648);       // 20000x128 f32 (10.24 MB)

    // ---- big scratch inside d_out (fully overwritten by out_kernel last) ----
    char* ob = (char*)d_out;
    float* agg   = (float*)(ob);                // 20000x256 f32 (20.48 MB)
    float* e1    = (float*)(ob + 20971520);     // 20000x256 f32 (20.48 MB)
    float* h     = (float*)(ob + 41943040);     // 20000x128 f32 (10.24 MB)
    int*   csr_j = (int*)  (ob + 52428800);     // 640000 i32 (2.56 MB)
    int*   csr_o = (int*)  (ob + 54988800);     // 640000 i32 (2.56 MB)

    hipMemsetAsync(deg, 0, NN * sizeof(int), stream);
    hipMemsetAsync(cur, 0, NN * sizeof(int), stream);

    // 1) h = relu([x|proto] @ lin1_W + lin1_b)      [20000,256]@[256,128]
    gemm_f32<true, true, true><<<dim3(313, 2), 256, 0, stream>>>(
        x, proto, lin1_W, lin1_b, h, NN, 128, 256);

    // 2) nw = sigmoid(h @ lin2_W + lin2_b)
    nw_kernel<<<5000, 256, 0, stream>>>(h, lin2_W, lin2_b, nw);

    // 3) degree histogram
    deg_kernel<<<(S + 255) / 256, 256, 0, stream>>>(ei, deg);

    // 4) Dinv per edge
    dinv_kernel<<<(NE + 255) / 256, 256, 0, stream>>>(ei, nw, Dinv);

    // 5) offsets + Binv
    scan_kernel<<<1, 1024, 0, stream>>>(deg, off, Binv);

    // 6) CSR fill
    fill_kernel<<<(S + 255) / 256, 256, 0, stream>>>(ei, off, cur, csr_j, csr_o);

    // 7) agg0
    agg0_kernel<<<NN, 256, 0, stream>>>(csr_j, csr_o, off, Binv, edge_rep, nf, agg);

    // 8) e1 = agg0 @ hc1_W                          [20000,256]@[256,256]
    gemm_f32<false, false, false><<<dim3(313, 4), 256, 0, stream>>>(
        agg, nullptr, hc1_W, nullptr, e1, NN, 256, 256);

    // 9) agg1
    agg1_kernel<<<NN, 256, 0, stream>>>(csr_j, csr_o, off, Binv, Dinv, e1, hc1_b, agg);

    // 10) e2 = agg1 @ hc2_W                         [20000,256]@[256,128]
    gemm_f32<false, false, false><<<dim3(313, 2), 256, 0, stream>>>(
        agg, nullptr, hc2_W, nullptr, e2, NN, 128, 256);

    // 11) final per-edge output (fully overwrites d_out)
    out_kernel<<<NE / 2, 256, 0, stream>>>(e2, Dinv, ei, hc2_b, out);
}